// Round 1
// baseline (348.714 us; speedup 1.0000x reference)
//
#include <hip/hip_runtime.h>

// out[b, t, h] = sum_{j=0..4} x[b, t+j, h] * attn[b, t+j]
// B=32, H=768, LENGTH=2048, PADDED=2052, fp32 in/out. Memory-bound streaming.
// TCHUNK=64: read amplification 68/64 = 1.0625.
//
// R1 change vs 332.0 µs baseline: x loads are now CACHED (plain loads), not
// nontemporal. Rationale: nt loads are no-allocate in L2/L3, so the 4-row
// chunk-boundary overlap (12.2 MB) was fetched from HBM twice. All 768 blocks
// are exactly co-resident (3/CU), so adjacent chunks of the same b stream
// concurrently -> cached first touch lets the re-read hit L2/L3. The m13
// 6.29 TB/s copy ceiling was also measured with cached loads.
// Stores stay nontemporal: out (201 MB) is never re-read and must not evict
// x lines from the 256 MB L3.

#define LEN     2048
#define WIDTH   5
#define PADDED  (LEN + WIDTH - 1)   // 2052
#define BATCH   32
#define HDIM    768
#define H4      (HDIM / 4)          // 192 float4 per row
#define TCHUNK  64
#define NCHUNK  (LEN / TCHUNK)      // 32

typedef float vfloat4 __attribute__((ext_vector_type(4)));

__global__ __launch_bounds__(256) void widthap_kernel(
    const vfloat4* __restrict__ x,
    const float*   __restrict__ attn,
    vfloat4*       __restrict__ out)
{
    const int tid   = blockIdx.x * blockDim.x + threadIdx.x;
    const int h4    = tid % H4;            // lane-contiguous -> coalesced
    const int rest  = tid / H4;
    const int b     = rest % BATCH;
    const int chunk = rest / BATCH;
    const int t0 = chunk * TCHUNK;

    const vfloat4* xp = x    + ((size_t)b * PADDED + t0) * H4 + h4;
    const float*   ap = attn +  (size_t)b * PADDED + t0;
    vfloat4*       op = out  + ((size_t)b * LEN    + t0) * H4 + h4;

    // ring of pre-weighted values w[j] = x[t0+j]*attn[t0+j]; each x read once
    vfloat4 w0, w1, w2, w3, w4;

    auto loadw = [&](int j) -> vfloat4 {
        const float   a = ap[j];                   // cached, wave-broadcast
        const vfloat4 v = xp[(size_t)j * H4];      // CACHED streaming 16B/lane
        return v * a;
    };

    w0 = loadw(0);
    w1 = loadw(1);
    w2 = loadw(2);
    w3 = loadw(3);

    #pragma unroll 8
    for (int i = 0; i < TCHUNK; ++i) {
        w4 = loadw(i + 4);
        vfloat4 s = w0 + w1 + w2 + w3 + w4;
        __builtin_nontemporal_store(s, &op[(size_t)i * H4]);   // streaming store
        w0 = w1; w1 = w2; w2 = w3; w3 = w4;
    }
}

extern "C" void kernel_launch(void* const* d_in, const int* in_sizes, int n_in,
                              void* d_out, int out_size, void* d_ws, size_t ws_size,
                              hipStream_t stream) {
    const vfloat4* x    = (const vfloat4*)d_in[0];  // (32,1,2052,768) fp32
    const float*   attn = (const float*)d_in[1];    // (32,2052) fp32
    vfloat4*       out  = (vfloat4*)d_out;          // (32,1,2048,768) fp32

    const int total_threads = H4 * BATCH * NCHUNK;    // 196608
    const int block = 256;
    const int grid  = total_threads / block;          // 768 = 3 blocks/CU
    widthap_kernel<<<grid, block, 0, stream>>>(x, attn, out);
}

// Round 2
// 331.923 us; speedup vs baseline: 1.0506x; 1.0506x over previous
//
#include <hip/hip_runtime.h>

// out[b, t, h] = sum_{j=0..4} x[b, t+j, h] * attn[b, t+j]
// B=32, H=768, LENGTH=2048, PADDED=2052, fp32 in/out. Memory-bound streaming.
//
// R2 vs R1 (125 us kernel, 2.46 TB/s, VGPR=36, Occ=26%):
//  - REVERT to nontemporal x loads (R1's cached loads cost +17 us headline:
//    cache allocation pressure on a pure stream; nt keeps L1/L2 clean).
//  - Latency-bound, not BW-bound fix #1: explicit 8-deep load batching.
//    R1's VGPR=36 proves the compiler kept only ~2-3 loads in flight despite
//    "unroll 8" (ring + addrs left no registers). Phase-split groups of 8
//    (issue 8 independent nt loads -> then 8 mul/add/store) force ~8
//    outstanding 1 KiB wave-loads (~8 KB in flight per wave).
//  - Fix #2: TCHUNK 64->32: grid 768->1536 blocks = 6 blocks/CU = 24 waves/CU
//    (read amplification 36/32 = 1.125, +6% reads, irrelevant off-roofline).
// Stores stay nontemporal: out is never re-read.

#define LEN     2048
#define WIDTH   5
#define PADDED  (LEN + WIDTH - 1)   // 2052
#define BATCH   32
#define HDIM    768
#define H4      (HDIM / 4)          // 192 float4 per row
#define TCHUNK  32
#define NCHUNK  (LEN / TCHUNK)      // 64
#define GRP     8                   // loads in flight per wave

typedef float vfloat4 __attribute__((ext_vector_type(4)));

__global__ __launch_bounds__(256) void widthap_kernel(
    const vfloat4* __restrict__ x,
    const float*   __restrict__ attn,
    vfloat4*       __restrict__ out)
{
    const int tid   = blockIdx.x * blockDim.x + threadIdx.x;
    const int h4    = tid % H4;            // lane-contiguous -> coalesced
    const int rest  = tid / H4;            // 192 % 64 == 0 -> waves never straddle
    const int b     = rest % BATCH;
    const int chunk = rest / BATCH;
    const int t0 = chunk * TCHUNK;

    const vfloat4* xp = x    + ((size_t)b * PADDED + t0) * H4 + h4;
    const float*   ap = attn +  (size_t)b * PADDED + t0;
    vfloat4*       op = out  + ((size_t)b * LEN    + t0) * H4 + h4;

    // ring of pre-weighted values w[j] = x[t0+j]*attn[t0+j]
    vfloat4 w0, w1, w2, w3;
    {
        const float a0 = ap[0], a1 = ap[1], a2 = ap[2], a3 = ap[3];
        const vfloat4 v0 = __builtin_nontemporal_load(&xp[0 * (size_t)H4]);
        const vfloat4 v1 = __builtin_nontemporal_load(&xp[1 * (size_t)H4]);
        const vfloat4 v2 = __builtin_nontemporal_load(&xp[2 * (size_t)H4]);
        const vfloat4 v3 = __builtin_nontemporal_load(&xp[3 * (size_t)H4]);
        w0 = v0 * a0; w1 = v1 * a1; w2 = v2 * a2; w3 = v3 * a3;
    }

    #pragma unroll
    for (int g = 0; g < TCHUNK / GRP; ++g) {
        float   a[GRP];
        vfloat4 v[GRP];
        // phase 1a: attn scalars (oldest in vmcnt FIFO, L1 broadcast hits)
        #pragma unroll
        for (int k = 0; k < GRP; ++k)
            a[k] = ap[g * GRP + k + 4];
        // phase 1b: 8 independent streaming loads, all issued before any use
        #pragma unroll
        for (int k = 0; k < GRP; ++k)
            v[k] = __builtin_nontemporal_load(&xp[(size_t)(g * GRP + k + 4) * H4]);
        // phase 2: weight, 5-tap sum, streaming store
        #pragma unroll
        for (int k = 0; k < GRP; ++k) {
            const vfloat4 w4 = v[k] * a[k];
            const vfloat4 s  = w0 + w1 + w2 + w3 + w4;
            __builtin_nontemporal_store(s, &op[(size_t)(g * GRP + k) * H4]);
            w0 = w1; w1 = w2; w2 = w3; w3 = w4;
        }
    }
}

extern "C" void kernel_launch(void* const* d_in, const int* in_sizes, int n_in,
                              void* d_out, int out_size, void* d_ws, size_t ws_size,
                              hipStream_t stream) {
    const vfloat4* x    = (const vfloat4*)d_in[0];  // (32,1,2052,768) fp32
    const float*   attn = (const float*)d_in[1];    // (32,2052) fp32
    vfloat4*       out  = (vfloat4*)d_out;          // (32,1,2048,768) fp32

    const int total_threads = H4 * BATCH * NCHUNK;    // 393216
    const int block = 256;
    const int grid  = total_threads / block;          // 1536 = 6 blocks/CU
    widthap_kernel<<<grid, block, 0, stream>>>(x, attn, out);
}